// Round 7
// baseline (349.082 us; speedup 1.0000x reference)
//
#include <hip/hip_runtime.h>
#include <hip/hip_fp16.h>
#include <cstdint>
#include <cstddef>

#define NN 50000
#define NE 800000
#define RNG 8
#define RSZ ((NN + RNG - 1) / RNG)
#define CPR 256

typedef _Float16 half8 __attribute__((ext_vector_type(8)));
typedef float    f32x4 __attribute__((ext_vector_type(4)));

static __device__ __forceinline__ float lrelu02(float x){ return x > 0.f ? x : 0.2f*x; }

static __device__ __forceinline__ float2 h2f(uint32_t u){
  __half2 h = *reinterpret_cast<__half2*>(&u);
  return __half22float2(h);
}
static __device__ __forceinline__ uint32_t f2h(float a, float b){
  __half2 h = __floats2half2_rn(a, b);
  return *reinterpret_cast<uint32_t*>(&h);
}
// accumulate 8 halves (one uint4) into acc[0..8)
static __device__ __forceinline__ void acc8p(float* acc, uint4 raw, float p){
  float2 f0=h2f(raw.x), f1=h2f(raw.y), f2=h2f(raw.z), f3=h2f(raw.w);
  acc[0]+=p*f0.x; acc[1]+=p*f0.y; acc[2]+=p*f1.x; acc[3]+=p*f1.y;
  acc[4]+=p*f2.x; acc[5]+=p*f2.y; acc[6]+=p*f3.x; acc[7]+=p*f3.y;
}
static __device__ __forceinline__ void acc8s(float* acc, uint4 raw){
  float2 f0=h2f(raw.x), f1=h2f(raw.y), f2=h2f(raw.z), f3=h2f(raw.w);
  acc[0]+=f0.x; acc[1]+=f0.y; acc[2]+=f1.x; acc[3]+=f1.y;
  acc[4]+=f2.x; acc[5]+=f2.y; acc[6]+=f3.x; acc[7]+=f3.y;
}

// ---------------- weight pre-swizzle + cnt zero -------------------------------------
// Bsw[((k0/32)*(N/16)+ct)*512 + lane*8 + j] = B[k0+(lane>>4)*8+j][ct*16+(lane&15)]
__global__ __launch_bounds__(256) void pack_all_kernel(
    const float* __restrict__ W1, const float* __restrict__ Wg,
    const float* __restrict__ W2, const float* __restrict__ Wf,
    _Float16* __restrict__ B1, _Float16* __restrict__ B2,
    _Float16* __restrict__ B3, _Float16* __restrict__ B4,
    int* __restrict__ cnt)
{
  const int b = blockIdx.x;
  if (b >= 240){                         // zero cnt (replaces hipMemsetAsync)
    const int i = (b - 240)*256 + threadIdx.x;
    if (i < NN) cnt[i] = 0;
    return;
  }
  const float* B; _Float16* O; int K, N, base;
  if      (b < 96)  { B = W1; O = B1; K = 192; N = 128; base = 0;   }
  else if (b < 160) { B = Wg; O = B2; K = 128; N = 128; base = 96;  }
  else if (b < 192) { B = W2; O = B3; K = 128; N = 64;  base = 160; }
  else              { B = Wf; O = B4; K = 64;  N = 192; base = 192; }
  const int i = (b - base)*256 + threadIdx.x;
  if (i >= K*N) return;
  const int j    = i & 7;
  const int lane = (i >> 3) & 63;
  const int tile = i >> 9;
  const int ntl  = N >> 4;
  const int ct   = tile % ntl;
  const int k0   = (tile / ntl) << 5;
  const int k = k0 + ((lane >> 4) << 3) + j;
  const int n = (ct << 4) + (lane & 15);
  O[i] = (_Float16)B[(size_t)k*N + n];
}

// ---------------- CSR preprocessing: range-partitioned (XCD-local atomics) -----------
__global__ __launch_bounds__(256) void count_kernel(const int* __restrict__ dst,
                                                    int* __restrict__ cnt, int E){
  const int r  = blockIdx.x % RNG;
  const int i  = blockIdx.x / RNG;
  const int lo = r * RSZ;
  const int hi = min(lo + RSZ, NN);
  const int cs = (E + CPR - 1) / CPR;
  const int e1 = min((i+1)*cs, E);
  for (int e = i*cs + threadIdx.x; e < e1; e += 256){
    const int d = dst[e];
    if (d >= lo && d < hi) atomicAdd(&cnt[d], 1);
  }
}

__global__ __launch_bounds__(1024) void scan1_kernel(const int* __restrict__ cnt,
      int* __restrict__ incl, int* __restrict__ bsum, int N){
  __shared__ int tmp[1024];
  const int t = threadIdx.x;
  const int i = blockIdx.x*1024 + t;
  int v = (i < N) ? cnt[i] : 0;
  tmp[t] = v;
  __syncthreads();
  #pragma unroll
  for (int off = 1; off < 1024; off <<= 1){
    int u = (t >= off) ? tmp[t-off] : 0;
    __syncthreads();
    tmp[t] += u;
    __syncthreads();
  }
  if (i < N) incl[i] = tmp[t];
  if (t == 1023) bsum[blockIdx.x] = tmp[t];
}

// scan3 with inlined bsum prefix (wave 0 recomputes the 49-entry exclusive scan)
__global__ __launch_bounds__(256) void scan3_kernel(const int* __restrict__ cnt,
      const int* __restrict__ incl, const int* __restrict__ bsum,
      int* __restrict__ rp, int* __restrict__ fillp,
      float* __restrict__ dinv, int N, int NB){
  __shared__ int pre[64];
  const int t = threadIdx.x;
  if (t < 64){
    int own = (t < NB) ? bsum[t] : 0;
    int v = own;
    #pragma unroll
    for (int off = 1; off < 64; off <<= 1){
      int u = __shfl_up(v, off, 64);
      if (t >= off) v += u;
    }
    pre[t] = v - own;
  }
  __syncthreads();
  const int i = blockIdx.x*256 + t;
  if (i >= N) return;
  const int c = cnt[i];
  const int e = pre[i >> 10] + incl[i] - c;
  rp[i] = e; fillp[i] = e;
  dinv[i] = rsqrtf((float)(c + 1));
  if (i == N-1) rp[N] = e + c;
}

__global__ __launch_bounds__(256) void fill_kernel(const int* __restrict__ src,
      const int* __restrict__ dst, int* __restrict__ fillp,
      int* __restrict__ col, int E){
  const int r  = blockIdx.x % RNG;
  const int i  = blockIdx.x / RNG;
  const int lo = r * RSZ;
  const int hi = min(lo + RSZ, NN);
  const int cs = (E + CPR - 1) / CPR;
  const int e1 = min((i+1)*cs, E);
  for (int e = i*cs + threadIdx.x; e < e1; e += 256){
    const int d = dst[e];
    if (d >= lo && d < hi){
      const int s = src[e];
      const int pos = atomicAdd(&fillp[d], 1);
      col[pos] = s;
    }
  }
}

// ---------------- MFMA f16 GEMM, LDS-free, BM=128 (B-fragment reg reuse) -------------
// Two 64-row tiles per block share each B fragment (2 MFMA per B load, B L2 traffic
// halved). B pre-swizzled in fragment order; no LDS, no barriers.
// Fragments: A[m=lane&15][k=quad*8+j]; C/D: col=lane&15, row=quad*4+reg.
template<bool AHALF, int K>
static __device__ __forceinline__ half8 load_afrag(const void* Av, int row, int M,
                                                   int k0, int quad){
  union { half8 h; uint4 u; uint32_t w[4]; } ua;
  if (row < M){
    if constexpr (AHALF){
      ua.u = *(const uint4*)((const _Float16*)Av + (size_t)row*K + k0 + quad*8);
    } else {
      const float* Arow = (const float*)Av + (size_t)row*K;
      const float4 va = *(const float4*)(Arow + k0 + quad*8);
      const float4 vb = *(const float4*)(Arow + k0 + quad*8 + 4);
      ua.w[0] = f2h(va.x, va.y);
      ua.w[1] = f2h(va.z, va.w);
      ua.w[2] = f2h(vb.x, vb.y);
      ua.w[3] = f2h(vb.z, vb.w);
    }
  } else {
    ua.u = make_uint4(0u,0u,0u,0u);
  }
  return ua.h;
}

template<int K, int NT, bool AHALF, bool HALF_OUT, bool DOTS>
__global__ __launch_bounds__(256) void gemm_mfma_kernel(
    const void* __restrict__ Av, const _Float16* __restrict__ Bsw,
    const float* __restrict__ bias, const float* __restrict__ rowscale,
    const float* __restrict__ avs, const float* __restrict__ avd,
    float* __restrict__ al, float* __restrict__ ar,
    void* __restrict__ Cv, int M, int N)
{
  constexpr int NTL = NT*4;
  const int bm = blockIdx.x * 128;
  const int t  = threadIdx.x;
  const int w    = t >> 6;
  const int lane = t & 63;
  const int m    = lane & 15;
  const int quad = lane >> 4;

  f32x4 acc0[NTL], acc1[NTL];
  #pragma unroll
  for (int ct = 0; ct < NTL; ++ct){
    acc0[ct] = (f32x4){0.f,0.f,0.f,0.f};
    acc1[ct] = (f32x4){0.f,0.f,0.f,0.f};
  }

  const int r0 = bm + w*16 + m;
  const int r1 = r0 + 64;
  const _Float16* bp = Bsw + lane*8;

  #pragma unroll
  for (int k0 = 0; k0 < K; k0 += 32){
    const half8 a0 = load_afrag<AHALF, K>(Av, r0, M, k0, quad);
    const half8 a1 = load_afrag<AHALF, K>(Av, r1, M, k0, quad);
    #pragma unroll
    for (int ct = 0; ct < NTL; ++ct){
      const half8 bf = *(const half8*)(bp + ((size_t)((k0>>5)*NTL + ct))*512);
      acc0[ct] = __builtin_amdgcn_mfma_f32_16x16x32_f16(a0, bf, acc0[ct], 0, 0, 0);
      acc1[ct] = __builtin_amdgcn_mfma_f32_16x16x32_f16(a1, bf, acc1[ct], 0, 0, 0);
    }
  }

  // epilogue per row-tile: C[row=RB+4*quad+reg][col=16ct+m]
#define EPILOG(ACC, RB, DAL, DAR)                                              \
  {                                                                            \
    float rs[4];                                                               \
    _Pragma("unroll")                                                          \
    for (int reg = 0; reg < 4; ++reg){                                         \
      const int r = (RB) + quad*4 + reg;                                       \
      rs[reg] = (rowscale && r < M) ? rowscale[r] : 1.f;                       \
    }                                                                          \
    _Pragma("unroll")                                                          \
    for (int ct = 0; ct < NTL; ++ct){                                          \
      const int colg = ct*16 + m;                                              \
      const float bv = bias ? bias[colg] : 0.f;                                \
      float s_c = 0.f, d_c = 0.f;                                              \
      if constexpr (DOTS){ s_c = avs[colg]; d_c = avd[colg]; }                 \
      _Pragma("unroll")                                                        \
      for (int reg = 0; reg < 4; ++reg){                                       \
        const int r = (RB) + quad*4 + reg;                                     \
        if (r < M){                                                            \
          const float v = rs[reg]*ACC[ct][reg] + bv;                           \
          if constexpr (DOTS){ DAL[reg] += v*s_c; DAR[reg] += v*d_c; }         \
          if constexpr (HALF_OUT){                                             \
            ((__half*)Cv)[(size_t)r*N + colg] = __float2half(v);               \
          } else {                                                             \
            ((float*)Cv)[(size_t)r*N + colg] = v;                              \
          }                                                                    \
        }                                                                      \
      }                                                                        \
    }                                                                          \
    if constexpr (DOTS){                                                       \
      _Pragma("unroll")                                                        \
      for (int off = 1; off < 16; off <<= 1){                                  \
        _Pragma("unroll")                                                      \
        for (int reg = 0; reg < 4; ++reg){                                     \
          DAL[reg] += __shfl_xor(DAL[reg], off, 64);                           \
          DAR[reg] += __shfl_xor(DAR[reg], off, 64);                           \
        }                                                                      \
      }                                                                        \
      if (m == 0){                                                             \
        _Pragma("unroll")                                                      \
        for (int reg = 0; reg < 4; ++reg){                                     \
          const int r = (RB) + quad*4 + reg;                                   \
          if (r < M){ al[r] = DAL[reg]; ar[r] = DAR[reg]; }                    \
        }                                                                      \
      }                                                                        \
    }                                                                          \
  }

  float dal0[4] = {0.f,0.f,0.f,0.f}, dar0[4] = {0.f,0.f,0.f,0.f};
  float dal1[4] = {0.f,0.f,0.f,0.f}, dar1[4] = {0.f,0.f,0.f,0.f};
  EPILOG(acc0, bm + w*16,      dal0, dar0)
  EPILOG(acc1, bm + w*16 + 64, dal1, dar1)
#undef EPILOG
}

// ---------------- GCN aggregation F=128: 8-LANE GROUP PER NODE (2x MLP) --------------
// Lane owns 16 channels (2 uint4 per neighbor row); 8 nodes per wave.
__global__ __launch_bounds__(256) void gcn_agg128_kernel(
    const __half* __restrict__ H, const int* __restrict__ rp, const int* __restrict__ col,
    const float* __restrict__ dinv, const float* __restrict__ bias,
    __half* __restrict__ out, int N)
{
  const int t  = threadIdx.x;
  const int n  = blockIdx.x * 32 + (t >> 3);
  const int gl = t & 7;
  if (n >= N) return;
  const float dn = dinv[n];
  float acc[16];
  {
    const __half* Hn = H + (size_t)n*128 + gl*16;
    uint4 ra = *(const uint4*)Hn;
    uint4 rb = *(const uint4*)(Hn + 8);
    float2 f0=h2f(ra.x), f1=h2f(ra.y), f2=h2f(ra.z), f3=h2f(ra.w);
    acc[0]=f0.x; acc[1]=f0.y; acc[2]=f1.x; acc[3]=f1.y;
    acc[4]=f2.x; acc[5]=f2.y; acc[6]=f3.x; acc[7]=f3.y;
    float2 g0=h2f(rb.x), g1=h2f(rb.y), g2=h2f(rb.z), g3=h2f(rb.w);
    acc[8]=g0.x; acc[9]=g0.y; acc[10]=g1.x; acc[11]=g1.y;
    acc[12]=g2.x; acc[13]=g2.y; acc[14]=g3.x; acc[15]=g3.y;
  }
  const int s0 = rp[n], s1 = rp[n+1];
  for (int c0 = s0; c0 < s1; c0 += 8){
    const int nc = min(8, s1 - c0);
    int sl = (gl < nc) ? col[c0 + gl] : 0;
    #pragma unroll 2
    for (int j = 0; j < nc; ++j){
      const int s = __shfl(sl, j, 8);
      const __half* Hs = H + (size_t)s*128 + gl*16;
      uint4 ra = *(const uint4*)Hs;
      uint4 rb = *(const uint4*)(Hs + 8);
      acc8s(acc, ra);
      acc8s(acc + 8, rb);
    }
  }
  const float* bp = bias + gl*16;
  float4 b0 = *(const float4*)(bp);
  float4 b1 = *(const float4*)(bp + 4);
  float4 b2 = *(const float4*)(bp + 8);
  float4 b3 = *(const float4*)(bp + 12);
  uint4 oa, ob;
  oa.x = f2h(dn*acc[0]  + b0.x, dn*acc[1]  + b0.y);
  oa.y = f2h(dn*acc[2]  + b0.z, dn*acc[3]  + b0.w);
  oa.z = f2h(dn*acc[4]  + b1.x, dn*acc[5]  + b1.y);
  oa.w = f2h(dn*acc[6]  + b1.z, dn*acc[7]  + b1.w);
  ob.x = f2h(dn*acc[8]  + b2.x, dn*acc[9]  + b2.y);
  ob.y = f2h(dn*acc[10] + b2.z, dn*acc[11] + b2.w);
  ob.z = f2h(dn*acc[12] + b3.x, dn*acc[13] + b3.y);
  ob.w = f2h(dn*acc[14] + b3.z, dn*acc[15] + b3.w);
  __half* op = out + (size_t)n*128 + gl*16;
  *(uint4*)op       = oa;
  *(uint4*)(op + 8) = ob;
}

// ---------------- GCN aggregation F=64: 4-LANE GROUP PER NODE (2x MLP) ---------------
__global__ __launch_bounds__(256) void gcn_agg64_kernel(
    const __half* __restrict__ H, const int* __restrict__ rp, const int* __restrict__ col,
    const float* __restrict__ dinv, const float* __restrict__ bias,
    __half* __restrict__ out, int N)
{
  const int t  = threadIdx.x;
  const int n  = blockIdx.x * 64 + (t >> 2);
  const int gl = t & 3;
  if (n >= N) return;
  const float dn = dinv[n];
  float acc[16];
  {
    const __half* Hn = H + (size_t)n*64 + gl*16;
    uint4 ra = *(const uint4*)Hn;
    uint4 rb = *(const uint4*)(Hn + 8);
    float2 f0=h2f(ra.x), f1=h2f(ra.y), f2=h2f(ra.z), f3=h2f(ra.w);
    acc[0]=f0.x; acc[1]=f0.y; acc[2]=f1.x; acc[3]=f1.y;
    acc[4]=f2.x; acc[5]=f2.y; acc[6]=f3.x; acc[7]=f3.y;
    float2 g0=h2f(rb.x), g1=h2f(rb.y), g2=h2f(rb.z), g3=h2f(rb.w);
    acc[8]=g0.x; acc[9]=g0.y; acc[10]=g1.x; acc[11]=g1.y;
    acc[12]=g2.x; acc[13]=g2.y; acc[14]=g3.x; acc[15]=g3.y;
  }
  const int s0 = rp[n], s1 = rp[n+1];
  for (int c0 = s0; c0 < s1; c0 += 4){
    const int nc = min(4, s1 - c0);
    int sl = (gl < nc) ? col[c0 + gl] : 0;
    #pragma unroll 2
    for (int j = 0; j < nc; ++j){
      const int s = __shfl(sl, j, 4);
      const __half* Hs = H + (size_t)s*64 + gl*16;
      uint4 ra = *(const uint4*)Hs;
      uint4 rb = *(const uint4*)(Hs + 8);
      acc8s(acc, ra);
      acc8s(acc + 8, rb);
    }
  }
  const float* bp = bias + gl*16;
  float4 b0 = *(const float4*)(bp);
  float4 b1 = *(const float4*)(bp + 4);
  float4 b2 = *(const float4*)(bp + 8);
  float4 b3 = *(const float4*)(bp + 12);
  uint4 oa, ob;
  oa.x = f2h(dn*acc[0]  + b0.x, dn*acc[1]  + b0.y);
  oa.y = f2h(dn*acc[2]  + b0.z, dn*acc[3]  + b0.w);
  oa.z = f2h(dn*acc[4]  + b1.x, dn*acc[5]  + b1.y);
  oa.w = f2h(dn*acc[6]  + b1.z, dn*acc[7]  + b1.w);
  ob.x = f2h(dn*acc[8]  + b2.x, dn*acc[9]  + b2.y);
  ob.y = f2h(dn*acc[10] + b2.z, dn*acc[11] + b2.w);
  ob.z = f2h(dn*acc[12] + b3.x, dn*acc[13] + b3.y);
  ob.w = f2h(dn*acc[14] + b3.z, dn*acc[15] + b3.w);
  __half* op = out + (size_t)n*64 + gl*16;
  *(uint4*)op       = oa;
  *(uint4*)(op + 8) = ob;
}

// ---------------- GAT aggregation: 8-LANE GROUP PER NODE (2x MLP) --------------------
__global__ __launch_bounds__(256) void gat_agg_kernel(
    const __half* __restrict__ HG, const int* __restrict__ rp, const int* __restrict__ col,
    const float* __restrict__ al, const float* __restrict__ ar,
    const float* __restrict__ bias, __half* __restrict__ out, int N)
{
  const int t  = threadIdx.x;
  const int n  = blockIdx.x * 32 + (t >> 3);
  const int gl = t & 7;
  if (n >= N) return;
  const float arn = ar[n];
  const float pself = __expf(lrelu02(al[n] + arn));
  float lpart = 0.f;
  float acc[16];
  {
    const __half* Hn = HG + (size_t)n*128 + gl*16;
    uint4 ra = *(const uint4*)Hn;
    uint4 rb = *(const uint4*)(Hn + 8);
    float2 f0=h2f(ra.x), f1=h2f(ra.y), f2=h2f(ra.z), f3=h2f(ra.w);
    acc[0]=pself*f0.x; acc[1]=pself*f0.y; acc[2]=pself*f1.x; acc[3]=pself*f1.y;
    acc[4]=pself*f2.x; acc[5]=pself*f2.y; acc[6]=pself*f3.x; acc[7]=pself*f3.y;
    float2 g0=h2f(rb.x), g1=h2f(rb.y), g2=h2f(rb.z), g3=h2f(rb.w);
    acc[8]=pself*g0.x; acc[9]=pself*g0.y; acc[10]=pself*g1.x; acc[11]=pself*g1.y;
    acc[12]=pself*g2.x; acc[13]=pself*g2.y; acc[14]=pself*g3.x; acc[15]=pself*g3.y;
  }
  const int s0 = rp[n], s1 = rp[n+1];
  for (int c0 = s0; c0 < s1; c0 += 8){
    const int nc = min(8, s1 - c0);
    int   sl = (gl < nc) ? col[c0 + gl] : 0;
    float pl = (gl < nc) ? __expf(lrelu02(al[sl] + arn)) : 0.f;
    lpart += pl;
    #pragma unroll 2
    for (int j = 0; j < nc; ++j){
      const int   s = __shfl(sl, j, 8);
      const float p = __shfl(pl, j, 8);
      const __half* Hs = HG + (size_t)s*128 + gl*16;
      uint4 ra = *(const uint4*)Hs;
      uint4 rb = *(const uint4*)(Hs + 8);
      acc8p(acc, ra, p);
      acc8p(acc + 8, rb, p);
    }
  }
  #pragma unroll
  for (int off = 4; off > 0; off >>= 1) lpart += __shfl_xor(lpart, off, 8);
  const float inv = 1.f / (pself + lpart);
  const float* bp = bias + gl*16;
  float4 b0 = *(const float4*)(bp);
  float4 b1 = *(const float4*)(bp + 4);
  float4 b2 = *(const float4*)(bp + 8);
  float4 b3 = *(const float4*)(bp + 12);
  uint4 oa, ob;
  oa.x = f2h(fmaxf(acc[0]*inv  + b0.x, 0.f), fmaxf(acc[1]*inv  + b0.y, 0.f));
  oa.y = f2h(fmaxf(acc[2]*inv  + b0.z, 0.f), fmaxf(acc[3]*inv  + b0.w, 0.f));
  oa.z = f2h(fmaxf(acc[4]*inv  + b1.x, 0.f), fmaxf(acc[5]*inv  + b1.y, 0.f));
  oa.w = f2h(fmaxf(acc[6]*inv  + b1.z, 0.f), fmaxf(acc[7]*inv  + b1.w, 0.f));
  ob.x = f2h(fmaxf(acc[8]*inv  + b2.x, 0.f), fmaxf(acc[9]*inv  + b2.y, 0.f));
  ob.y = f2h(fmaxf(acc[10]*inv + b2.z, 0.f), fmaxf(acc[11]*inv + b2.w, 0.f));
  ob.z = f2h(fmaxf(acc[12]*inv + b3.x, 0.f), fmaxf(acc[13]*inv + b3.y, 0.f));
  ob.w = f2h(fmaxf(acc[14]*inv + b3.z, 0.f), fmaxf(acc[15]*inv + b3.w, 0.f));
  __half* op = out + (size_t)n*128 + gl*16;
  *(uint4*)op       = oa;
  *(uint4*)(op + 8) = ob;
}

// ---------------- launch ----------------
extern "C" void kernel_launch(void* const* d_in, const int* in_sizes, int n_in,
                              void* d_out, int out_size, void* d_ws, size_t ws_size,
                              hipStream_t stream)
{
  const float* x     = (const float*)d_in[0];
  const int*   ei    = (const int*)d_in[1];
  const float* W1    = (const float*)d_in[2];
  const float* b1    = (const float*)d_in[3];
  const float* Wg    = (const float*)d_in[4];
  const float* a_src = (const float*)d_in[5];
  const float* a_dst = (const float*)d_in[6];
  const float* bg    = (const float*)d_in[7];
  const float* W2    = (const float*)d_in[8];
  const float* b2    = (const float*)d_in[9];
  const float* Wf    = (const float*)d_in[10];
  const float* bf    = (const float*)d_in[11];
  const int N = NN, E = NE;
  const int* src = ei;
  const int* dst = ei + E;

  char* p = (char*)d_ws;
  auto alloc = [&](size_t bytes)->char*{
    char* r = p; p += (bytes + 511) & ~size_t(511); return r;
  };
  int*      cnt   = (int*)     alloc((size_t)N*4);
  int*      incl  = (int*)     alloc((size_t)N*4);
  int*      bsum  = (int*)     alloc(64*4);
  int*      rp    = (int*)     alloc((size_t)(N+1)*4);
  int*      fillp = (int*)     alloc((size_t)N*4);
  int*      col   = (int*)     alloc((size_t)E*4);
  float*    dinv  = (float*)   alloc((size_t)N*4);
  float*    alar_ = (float*)   alloc((size_t)N*8);
  __half*   H16   = (__half*)  alloc((size_t)N*128*2);
  __half*   Hb    = (__half*)  alloc((size_t)N*128*2);
  _Float16* B1    = (_Float16*)alloc(24576*2);
  _Float16* B2    = (_Float16*)alloc(16384*2);
  _Float16* B3    = (_Float16*)alloc(8192*2);
  _Float16* B4    = (_Float16*)alloc(12288*2);
  float*    al    = alar_;
  float*    ar    = alar_ + N;

  const int NB = (N + 1023) / 1024;

  pack_all_kernel<<<240 + (NN + 255)/256, 256, 0, stream>>>(
      W1, Wg, W2, Wf, B1, B2, B3, B4, cnt);
  count_kernel<<<RNG*CPR, 256, 0, stream>>>(dst, cnt, E);
  scan1_kernel<<<NB, 1024, 0, stream>>>(cnt, incl, bsum, N);
  scan3_kernel<<<(N+255)/256, 256, 0, stream>>>(cnt, incl, bsum, rp, fillp, dinv, N, NB);
  fill_kernel<<<RNG*CPR, 256, 0, stream>>>(src, dst, fillp, col, E);

  const int gm  = (N + 127) / 128;
  const int g32 = (N + 31) / 32;
  const int g64 = (N + 63) / 64;

  // GEMM1: H16 = fp16( dinv ⊙ (x @ W1) )  [K=192, NT=2 -> N=128], fp32 A
  gemm_mfma_kernel<192,2,false,true,false><<<gm, 256, 0, stream>>>(
      x, B1, nullptr, dinv, nullptr, nullptr, nullptr, nullptr, H16, N, 128);
  // AGG1 (GCN): H16 -> Hb (+b1), fp16
  gcn_agg128_kernel<<<g32, 256, 0, stream>>>(H16, rp, col, dinv, b1, Hb, N);
  // GEMM2: H16 = fp16( Hb @ Wg ) (HG), fp16 A, fused al/ar (direct store)
  gemm_mfma_kernel<128,2,true,true,true><<<gm, 256, 0, stream>>>(
      Hb, B2, nullptr, nullptr, a_src, a_dst, al, ar, H16, N, 128);
  // GAT: H16 -> Hb (+bg, relu fused), fp16
  gat_agg_kernel<<<g32, 256, 0, stream>>>(H16, rp, col, al, ar, bg, Hb, N);
  // GEMM3: H16 = fp16( dinv ⊙ (Hb @ W2) )  [K=128, NT=1 -> N=64], fp16 A
  gemm_mfma_kernel<128,1,true,true,false><<<gm, 256, 0, stream>>>(
      Hb, B3, nullptr, dinv, nullptr, nullptr, nullptr, nullptr, H16, N, 64);
  // AGG2 (GCN): H16 -> Hb (+b2), fp16, F=64
  gcn_agg64_kernel<<<g64, 256, 0, stream>>>(H16, rp, col, dinv, b2, Hb, N);
  // GEMM4: out = Hb @ Wf + bf (fp32 out)  [K=64, NT=3 -> N=192], fp16 A
  gemm_mfma_kernel<64,3,true,false,false><<<gm, 256, 0, stream>>>(
      Hb, B4, bf, nullptr, nullptr, nullptr, nullptr, nullptr, d_out, N, 192);
}

// Round 8
// 322.950 us; speedup vs baseline: 1.0809x; 1.0809x over previous
//
#include <hip/hip_runtime.h>
#include <hip/hip_fp16.h>
#include <cstdint>
#include <cstddef>

#define NN 50000
#define NE 800000
#define RNG 8
#define RSZ ((NN + RNG - 1) / RNG)
#define CPR 256
#define FILLB (RNG*CPR)

typedef _Float16 half8 __attribute__((ext_vector_type(8)));
typedef float    f32x4 __attribute__((ext_vector_type(4)));

static __device__ __forceinline__ float lrelu02(float x){ return x > 0.f ? x : 0.2f*x; }

static __device__ __forceinline__ float2 h2f(uint32_t u){
  __half2 h = *reinterpret_cast<__half2*>(&u);
  return __half22float2(h);
}
static __device__ __forceinline__ uint32_t f2h(float a, float b){
  __half2 h = __floats2half2_rn(a, b);
  return *reinterpret_cast<uint32_t*>(&h);
}
// accumulate 8 halves (one uint4) into acc[0..8)
static __device__ __forceinline__ void acc8p(float* acc, uint4 raw, float p){
  float2 f0=h2f(raw.x), f1=h2f(raw.y), f2=h2f(raw.z), f3=h2f(raw.w);
  acc[0]+=p*f0.x; acc[1]+=p*f0.y; acc[2]+=p*f1.x; acc[3]+=p*f1.y;
  acc[4]+=p*f2.x; acc[5]+=p*f2.y; acc[6]+=p*f3.x; acc[7]+=p*f3.y;
}
static __device__ __forceinline__ void acc8s(float* acc, uint4 raw){
  float2 f0=h2f(raw.x), f1=h2f(raw.y), f2=h2f(raw.z), f3=h2f(raw.w);
  acc[0]+=f0.x; acc[1]+=f0.y; acc[2]+=f1.x; acc[3]+=f1.y;
  acc[4]+=f2.x; acc[5]+=f2.y; acc[6]+=f3.x; acc[7]+=f3.y;
}

// ---------------- weight pre-swizzle + cnt zero -------------------------------------
// Bsw[((k0/32)*(N/16)+ct)*512 + lane*8 + j] = B[k0+(lane>>4)*8+j][ct*16+(lane&15)]
__global__ __launch_bounds__(256) void pack_all_kernel(
    const float* __restrict__ W1, const float* __restrict__ Wg,
    const float* __restrict__ W2, const float* __restrict__ Wf,
    _Float16* __restrict__ B1, _Float16* __restrict__ B2,
    _Float16* __restrict__ B3, _Float16* __restrict__ B4,
    int* __restrict__ cnt)
{
  const int b = blockIdx.x;
  if (b >= 240){                         // zero cnt (replaces hipMemsetAsync)
    const int i = (b - 240)*256 + threadIdx.x;
    if (i < NN) cnt[i] = 0;
    return;
  }
  const float* B; _Float16* O; int K, N, base;
  if      (b < 96)  { B = W1; O = B1; K = 192; N = 128; base = 0;   }
  else if (b < 160) { B = Wg; O = B2; K = 128; N = 128; base = 96;  }
  else if (b < 192) { B = W2; O = B3; K = 128; N = 64;  base = 160; }
  else              { B = Wf; O = B4; K = 64;  N = 192; base = 192; }
  const int i = (b - base)*256 + threadIdx.x;
  if (i >= K*N) return;
  const int j    = i & 7;
  const int lane = (i >> 3) & 63;
  const int tile = i >> 9;
  const int ntl  = N >> 4;
  const int ct   = tile % ntl;
  const int k0   = (tile / ntl) << 5;
  const int k = k0 + ((lane >> 4) << 3) + j;
  const int n = (ct << 4) + (lane & 15);
  O[i] = (_Float16)B[(size_t)k*N + n];
}

// ---------------- CSR preprocessing: range-partitioned (XCD-local atomics) -----------
__global__ __launch_bounds__(256) void count_kernel(const int* __restrict__ dst,
                                                    int* __restrict__ cnt, int E){
  const int r  = blockIdx.x % RNG;
  const int i  = blockIdx.x / RNG;
  const int lo = r * RSZ;
  const int hi = min(lo + RSZ, NN);
  const int cs = (E + CPR - 1) / CPR;
  const int e1 = min((i+1)*cs, E);
  for (int e = i*cs + threadIdx.x; e < e1; e += 256){
    const int d = dst[e];
    if (d >= lo && d < hi) atomicAdd(&cnt[d], 1);
  }
}

__global__ __launch_bounds__(1024) void scan1_kernel(const int* __restrict__ cnt,
      int* __restrict__ incl, int* __restrict__ bsum, int N){
  __shared__ int tmp[1024];
  const int t = threadIdx.x;
  const int i = blockIdx.x*1024 + t;
  int v = (i < N) ? cnt[i] : 0;
  tmp[t] = v;
  __syncthreads();
  #pragma unroll
  for (int off = 1; off < 1024; off <<= 1){
    int u = (t >= off) ? tmp[t-off] : 0;
    __syncthreads();
    tmp[t] += u;
    __syncthreads();
  }
  if (i < N) incl[i] = tmp[t];
  if (t == 1023) bsum[blockIdx.x] = tmp[t];
}

// scan3 with inlined bsum prefix (first wave recomputes the 49-entry exclusive scan)
__global__ __launch_bounds__(256) void scan3_kernel(const int* __restrict__ cnt,
      const int* __restrict__ incl, const int* __restrict__ bsum,
      int* __restrict__ rp, int* __restrict__ fillp,
      float* __restrict__ dinv, int N, int NB){
  __shared__ int pre[64];
  const int t = threadIdx.x;
  if (t < 64){
    int own = (t < NB) ? bsum[t] : 0;
    int v = own;
    #pragma unroll
    for (int off = 1; off < 64; off <<= 1){
      int u = __shfl_up(v, off, 64);
      if (t >= off) v += u;
    }
    pre[t] = v - own;
  }
  __syncthreads();
  const int i = blockIdx.x*256 + t;
  if (i >= N) return;
  const int c = cnt[i];
  const int e = pre[i >> 10] + incl[i] - c;
  rp[i] = e; fillp[i] = e;
  dinv[i] = rsqrtf((float)(c + 1));
  if (i == N-1) rp[N] = e + c;
}

// ---------------- MFMA f16 GEMM body, LDS-free (r6-proven, BM=64) --------------------
// B pre-swizzled in fragment order: per (k0,ct) each lane loads its 8-half B-fragment
// as one coalesced uint4 from global (L2-resident). No LDS, no barriers.
// Fragments: A[m=lane&15][k=quad*8+j]; C/D: col=lane&15, row=quad*4+reg.
template<int K, int NT, bool AHALF, bool HALF_OUT, bool DOTS>
static __device__ __forceinline__ void gemm_block(
    const void* __restrict__ Av, const _Float16* __restrict__ Bsw,
    const float* __restrict__ bias, const float* __restrict__ rowscale,
    const float* __restrict__ avs, const float* __restrict__ avd,
    float* __restrict__ al, float* __restrict__ ar,
    void* __restrict__ Cv, int M, int N, int bm, int t)
{
  constexpr int NTL = NT*4;
  const int w    = t >> 6;
  const int lane = t & 63;
  const int m    = lane & 15;
  const int quad = lane >> 4;

  f32x4 acc[NTL];
  #pragma unroll
  for (int ct = 0; ct < NTL; ++ct) acc[ct] = (f32x4){0.f,0.f,0.f,0.f};

  const int row = bm + w*16 + m;
  const _Float16* bp = Bsw + lane*8;

  #pragma unroll
  for (int k0 = 0; k0 < K; k0 += 32){
    union { half8 h; uint4 u; uint32_t w[4]; } ua;
    if constexpr (AHALF){
      if (row < M){
        ua.u = *(const uint4*)((const _Float16*)Av + (size_t)row*K + k0 + quad*8);
      } else {
        ua.u = make_uint4(0u,0u,0u,0u);
      }
    } else {
      if (row < M){
        const float* Arow = (const float*)Av + (size_t)row*K;
        const float4 va = *(const float4*)(Arow + k0 + quad*8);
        const float4 vb = *(const float4*)(Arow + k0 + quad*8 + 4);
        ua.w[0] = f2h(va.x, va.y);
        ua.w[1] = f2h(va.z, va.w);
        ua.w[2] = f2h(vb.x, vb.y);
        ua.w[3] = f2h(vb.z, vb.w);
      } else {
        ua.u = make_uint4(0u,0u,0u,0u);
      }
    }
    const half8 af = ua.h;
    #pragma unroll
    for (int ct = 0; ct < NTL; ++ct){
      const half8 bf = *(const half8*)(bp + ((size_t)((k0>>5)*NTL + ct))*512);
      acc[ct] = __builtin_amdgcn_mfma_f32_16x16x32_f16(af, bf, acc[ct], 0, 0, 0);
    }
  }

  // epilogue: C[row=bm+16w+4*quad+reg][col=16ct+m]
  float rs[4];
  #pragma unroll
  for (int reg = 0; reg < 4; ++reg){
    const int r = bm + w*16 + quad*4 + reg;
    rs[reg] = (rowscale && r < M) ? rowscale[r] : 1.f;
  }
  float dal[4] = {0.f,0.f,0.f,0.f};
  float dar[4] = {0.f,0.f,0.f,0.f};
  #pragma unroll
  for (int ct = 0; ct < NTL; ++ct){
    const int colg = ct*16 + m;
    const float bv = bias ? bias[colg] : 0.f;
    float s_c = 0.f, d_c = 0.f;
    if constexpr (DOTS){ s_c = avs[colg]; d_c = avd[colg]; }
    #pragma unroll
    for (int reg = 0; reg < 4; ++reg){
      const int r = bm + w*16 + quad*4 + reg;
      if (r < M){
        const float v = rs[reg]*acc[ct][reg] + bv;
        if constexpr (DOTS){ dal[reg] += v*s_c; dar[reg] += v*d_c; }
        if constexpr (HALF_OUT){
          ((__half*)Cv)[(size_t)r*N + colg] = __float2half(v);
        } else {
          ((float*)Cv)[(size_t)r*N + colg] = v;
        }
      }
    }
  }
  if constexpr (DOTS){
    #pragma unroll
    for (int off = 1; off < 16; off <<= 1){
      #pragma unroll
      for (int reg = 0; reg < 4; ++reg){
        dal[reg] += __shfl_xor(dal[reg], off, 64);
        dar[reg] += __shfl_xor(dar[reg], off, 64);
      }
    }
    if (m == 0){
      #pragma unroll
      for (int reg = 0; reg < 4; ++reg){
        const int r = bm + w*16 + quad*4 + reg;
        if (r < M){
          al[r] = dal[reg];                // block covers full N -> complete sums
          ar[r] = dar[reg];
        }
      }
    }
  }
}

template<int K, int NT, bool AHALF, bool HALF_OUT, bool DOTS>
__global__ __launch_bounds__(256) void gemm_mfma_kernel(
    const void* __restrict__ Av, const _Float16* __restrict__ Bsw,
    const float* __restrict__ bias, const float* __restrict__ rowscale,
    const float* __restrict__ avs, const float* __restrict__ avd,
    float* __restrict__ al, float* __restrict__ ar,
    void* __restrict__ Cv, int M, int N)
{
  gemm_block<K,NT,AHALF,HALF_OUT,DOTS>(Av, Bsw, bias, rowscale, avs, avd, al, ar,
                                       Cv, M, N, blockIdx.x*64, threadIdx.x);
}

// ---------------- FUSED: ranged fill (blocks 0..FILLB) || GEMM1 (rest) ---------------
// fill is atomic-latency-bound (VALU 0.4%, MFMA 0); GEMM1 depends only on pack+scan3.
// GEMM1 blocks backfill the idle MFMA/VALU/HBM pipes while fill blocks stall.
__global__ __launch_bounds__(256) void fill_gemm1_kernel(
    const int* __restrict__ src, const int* __restrict__ dst,
    int* __restrict__ fillp, int* __restrict__ col, int E,
    const float* __restrict__ A, const _Float16* __restrict__ B1,
    const float* __restrict__ dinv, __half* __restrict__ C, int M)
{
  if (blockIdx.x < FILLB){
    const int r  = blockIdx.x % RNG;
    const int i  = blockIdx.x / RNG;
    const int lo = r * RSZ;
    const int hi = min(lo + RSZ, NN);
    const int cs = (E + CPR - 1) / CPR;
    const int e1 = min((i+1)*cs, E);
    for (int e = i*cs + threadIdx.x; e < e1; e += 256){
      const int d = dst[e];
      if (d >= lo && d < hi){
        const int s = src[e];
        const int pos = atomicAdd(&fillp[d], 1);
        col[pos] = s;
      }
    }
    return;
  }
  const int bm = (blockIdx.x - FILLB) * 64;
  gemm_block<192,2,false,true,false>(A, B1, nullptr, dinv, nullptr, nullptr,
                                     nullptr, nullptr, C, M, 128, bm, threadIdx.x);
}

// ---------------- GCN aggregation F=128: ONE 16-LANE GROUP PER NODE (r6) -------------
__global__ __launch_bounds__(256) void gcn_agg128_kernel(
    const __half* __restrict__ H, const int* __restrict__ rp, const int* __restrict__ col,
    const float* __restrict__ dinv, const float* __restrict__ bias,
    __half* __restrict__ out, int N)
{
  const int t  = threadIdx.x;
  const int n  = blockIdx.x * 16 + (t >> 4);
  const int gl = t & 15;
  if (n >= N) return;
  const float dn = dinv[n];
  float acc[8];
  {
    uint4 raw = *(const uint4*)(H + (size_t)n*128 + gl*8);
    float2 f0=h2f(raw.x), f1=h2f(raw.y), f2=h2f(raw.z), f3=h2f(raw.w);
    acc[0]=f0.x; acc[1]=f0.y; acc[2]=f1.x; acc[3]=f1.y;
    acc[4]=f2.x; acc[5]=f2.y; acc[6]=f3.x; acc[7]=f3.y;
  }
  const int s0 = rp[n], s1 = rp[n+1];
  for (int c0 = s0; c0 < s1; c0 += 16){
    const int nc = min(16, s1 - c0);
    int sl = (gl < nc) ? col[c0 + gl] : 0;
    #pragma unroll 2
    for (int j = 0; j < nc; ++j){
      const int s = __shfl(sl, j, 16);
      acc8s(acc, *(const uint4*)(H + (size_t)s*128 + gl*8));
    }
  }
  const float* bp = bias + gl*8;
  float4 b0 = *(const float4*)(bp);
  float4 b1 = *(const float4*)(bp + 4);
  uint4 o;
  o.x = f2h(dn*acc[0] + b0.x, dn*acc[1] + b0.y);
  o.y = f2h(dn*acc[2] + b0.z, dn*acc[3] + b0.w);
  o.z = f2h(dn*acc[4] + b1.x, dn*acc[5] + b1.y);
  o.w = f2h(dn*acc[6] + b1.z, dn*acc[7] + b1.w);
  *(uint4*)(out + (size_t)n*128 + gl*8) = o;
}

// ---------------- GCN aggregation F=64: ONE 8-LANE GROUP PER NODE (r6) ---------------
__global__ __launch_bounds__(256) void gcn_agg64_kernel(
    const __half* __restrict__ H, const int* __restrict__ rp, const int* __restrict__ col,
    const float* __restrict__ dinv, const float* __restrict__ bias,
    __half* __restrict__ out, int N)
{
  const int t  = threadIdx.x;
  const int n  = blockIdx.x * 32 + (t >> 3);
  const int gl = t & 7;
  if (n >= N) return;
  const float dn = dinv[n];
  float acc[8];
  {
    uint4 raw = *(const uint4*)(H + (size_t)n*64 + gl*8);
    float2 f0=h2f(raw.x), f1=h2f(raw.y), f2=h2f(raw.z), f3=h2f(raw.w);
    acc[0]=f0.x; acc[1]=f0.y; acc[2]=f1.x; acc[3]=f1.y;
    acc[4]=f2.x; acc[5]=f2.y; acc[6]=f3.x; acc[7]=f3.y;
  }
  const int s0 = rp[n], s1 = rp[n+1];
  for (int c0 = s0; c0 < s1; c0 += 8){
    const int nc = min(8, s1 - c0);
    int sl = (gl < nc) ? col[c0 + gl] : 0;
    #pragma unroll 2
    for (int j = 0; j < nc; ++j){
      const int s = __shfl(sl, j, 8);
      acc8s(acc, *(const uint4*)(H + (size_t)s*64 + gl*8));
    }
  }
  const float* bp = bias + gl*8;
  float4 b0 = *(const float4*)(bp);
  float4 b1 = *(const float4*)(bp + 4);
  uint4 o;
  o.x = f2h(dn*acc[0] + b0.x, dn*acc[1] + b0.y);
  o.y = f2h(dn*acc[2] + b0.z, dn*acc[3] + b0.w);
  o.z = f2h(dn*acc[4] + b1.x, dn*acc[5] + b1.y);
  o.w = f2h(dn*acc[6] + b1.z, dn*acc[7] + b1.w);
  *(uint4*)(out + (size_t)n*64 + gl*8) = o;
}

// ---------------- GAT aggregation: ONE 16-LANE GROUP PER NODE (r6) -------------------
__global__ __launch_bounds__(256) void gat_agg_kernel(
    const __half* __restrict__ HG, const int* __restrict__ rp, const int* __restrict__ col,
    const float* __restrict__ al, const float* __restrict__ ar,
    const float* __restrict__ bias, __half* __restrict__ out, int N)
{
  const int t  = threadIdx.x;
  const int n  = blockIdx.x * 16 + (t >> 4);
  const int gl = t & 15;
  if (n >= N) return;
  const float arn = ar[n];
  const float pself = __expf(lrelu02(al[n] + arn));
  float lpart = 0.f;
  float acc[8];
  {
    uint4 raw = *(const uint4*)(HG + (size_t)n*128 + gl*8);
    float2 f0=h2f(raw.x), f1=h2f(raw.y), f2=h2f(raw.z), f3=h2f(raw.w);
    acc[0]=pself*f0.x; acc[1]=pself*f0.y; acc[2]=pself*f1.x; acc[3]=pself*f1.y;
    acc[4]=pself*f2.x; acc[5]=pself*f2.y; acc[6]=pself*f3.x; acc[7]=pself*f3.y;
  }
  const int s0 = rp[n], s1 = rp[n+1];
  for (int c0 = s0; c0 < s1; c0 += 16){
    const int nc = min(16, s1 - c0);
    int   sl = (gl < nc) ? col[c0 + gl] : 0;
    float pl = (gl < nc) ? __expf(lrelu02(al[sl] + arn)) : 0.f;
    lpart += pl;
    #pragma unroll 2
    for (int j = 0; j < nc; ++j){
      const int   s = __shfl(sl, j, 16);
      const float p = __shfl(pl, j, 16);
      acc8p(acc, *(const uint4*)(HG + (size_t)s*128 + gl*8), p);
    }
  }
  #pragma unroll
  for (int off = 8; off > 0; off >>= 1) lpart += __shfl_xor(lpart, off, 16);
  const float inv = 1.f / (pself + lpart);
  const float* bp = bias + gl*8;
  float4 b0 = *(const float4*)(bp);
  float4 b1 = *(const float4*)(bp + 4);
  uint4 o;
  o.x = f2h(fmaxf(acc[0]*inv + b0.x, 0.f), fmaxf(acc[1]*inv + b0.y, 0.f));
  o.y = f2h(fmaxf(acc[2]*inv + b0.z, 0.f), fmaxf(acc[3]*inv + b0.w, 0.f));
  o.z = f2h(fmaxf(acc[4]*inv + b1.x, 0.f), fmaxf(acc[5]*inv + b1.y, 0.f));
  o.w = f2h(fmaxf(acc[6]*inv + b1.z, 0.f), fmaxf(acc[7]*inv + b1.w, 0.f));
  *(uint4*)(out + (size_t)n*128 + gl*8) = o;
}

// ---------------- launch ----------------
extern "C" void kernel_launch(void* const* d_in, const int* in_sizes, int n_in,
                              void* d_out, int out_size, void* d_ws, size_t ws_size,
                              hipStream_t stream)
{
  const float* x     = (const float*)d_in[0];
  const int*   ei    = (const int*)d_in[1];
  const float* W1    = (const float*)d_in[2];
  const float* b1    = (const float*)d_in[3];
  const float* Wg    = (const float*)d_in[4];
  const float* a_src = (const float*)d_in[5];
  const float* a_dst = (const float*)d_in[6];
  const float* bg    = (const float*)d_in[7];
  const float* W2    = (const float*)d_in[8];
  const float* b2    = (const float*)d_in[9];
  const float* Wf    = (const float*)d_in[10];
  const float* bf    = (const float*)d_in[11];
  const int N = NN, E = NE;
  const int* src = ei;
  const int* dst = ei + E;

  char* p = (char*)d_ws;
  auto alloc = [&](size_t bytes)->char*{
    char* r = p; p += (bytes + 511) & ~size_t(511); return r;
  };
  int*      cnt   = (int*)     alloc((size_t)N*4);
  int*      incl  = (int*)     alloc((size_t)N*4);
  int*      bsum  = (int*)     alloc(64*4);
  int*      rp    = (int*)     alloc((size_t)(N+1)*4);
  int*      fillp = (int*)     alloc((size_t)N*4);
  int*      col   = (int*)     alloc((size_t)E*4);
  float*    dinv  = (float*)   alloc((size_t)N*4);
  float*    alar_ = (float*)   alloc((size_t)N*8);
  __half*   H16   = (__half*)  alloc((size_t)N*128*2);
  __half*   Hb    = (__half*)  alloc((size_t)N*128*2);
  _Float16* B1    = (_Float16*)alloc(24576*2);
  _Float16* B2    = (_Float16*)alloc(16384*2);
  _Float16* B3    = (_Float16*)alloc(8192*2);
  _Float16* B4    = (_Float16*)alloc(12288*2);
  float*    al    = alar_;
  float*    ar    = alar_ + N;

  const int NB = (N + 1023) / 1024;
  const int gm  = (N + 63) / 64;
  const int g16 = (N + 15) / 16;
  const int g32 = (N + 31) / 32;

  pack_all_kernel<<<240 + (NN + 255)/256, 256, 0, stream>>>(
      W1, Wg, W2, Wf, B1, B2, B3, B4, cnt);
  count_kernel<<<FILLB, 256, 0, stream>>>(dst, cnt, E);
  scan1_kernel<<<NB, 1024, 0, stream>>>(cnt, incl, bsum, N);
  scan3_kernel<<<(N+255)/256, 256, 0, stream>>>(cnt, incl, bsum, rp, fillp, dinv, N, NB);

  // FUSED: fill (graph) || GEMM1: H16 = fp16( dinv ⊙ (x @ W1) )
  fill_gemm1_kernel<<<FILLB + gm, 256, 0, stream>>>(
      src, dst, fillp, col, E, x, B1, dinv, H16, N);

  // AGG1 (GCN): H16 -> Hb (+b1), fp16
  gcn_agg128_kernel<<<g16, 256, 0, stream>>>(H16, rp, col, dinv, b1, Hb, N);
  // GEMM2: H16 = fp16( Hb @ Wg ) (HG), fp16 A, fused al/ar (direct store)
  gemm_mfma_kernel<128,2,true,true,true><<<gm, 256, 0, stream>>>(
      Hb, B2, nullptr, nullptr, a_src, a_dst, al, ar, H16, N, 128);
  // GAT: H16 -> Hb (+bg, relu fused), fp16
  gat_agg_kernel<<<g16, 256, 0, stream>>>(H16, rp, col, al, ar, bg, Hb, N);
  // GEMM3: H16 = fp16( dinv ⊙ (Hb @ W2) )  [K=128, NT=1 -> N=64], fp16 A
  gemm_mfma_kernel<128,1,true,true,false><<<gm, 256, 0, stream>>>(
      Hb, B3, nullptr, dinv, nullptr, nullptr, nullptr, nullptr, H16, N, 64);
  // AGG2 (GCN): H16 -> Hb (+b2), fp16, F=64
  gcn_agg64_kernel<<<g32, 256, 0, stream>>>(H16, rp, col, dinv, b2, Hb, N);
  // GEMM4: out = Hb @ Wf + bf (fp32 out)  [K=64, NT=3 -> N=192], fp16 A
  gemm_mfma_kernel<64,3,true,false,false><<<gm, 256, 0, stream>>>(
      Hb, B4, bf, nullptr, nullptr, nullptr, nullptr, nullptr, d_out, N, 192);
}